// Round 11
// baseline (1598.723 us; speedup 1.0000x reference)
//
#include <hip/hip_runtime.h>
#include <cstdint>

#pragma clang fp contract(off)

#define N_PTS 8192
#define B_SZ  4
#define K_NN  20
#define O_CH  64
#define QW    64
#define NWAVE 8
#define WARM  64
#define CAPQ  120
#define EPS   0.05f
#define P1END 2048
#define CHUNK 512

typedef unsigned long long u64k;
typedef unsigned short u16;
typedef __attribute__((ext_vector_type(8))) __bf16 bf16x8;
typedef __attribute__((ext_vector_type(8))) unsigned short u16x8;
typedef __attribute__((ext_vector_type(4))) float f32x4;

__device__ __forceinline__ u16 bf16_rn(float v) {          // RN-even, no NaN inputs
  unsigned u = __float_as_uint(v);
  return (u16)((u + 0x7FFFu + ((u >> 16) & 1u)) >> 16);
}
__device__ __forceinline__ float bf16_tof(u16 b) {
  return __uint_as_float(((unsigned)b) << 16);
}

// pd = -xx_n - (-2*dot) - xx_m with numpy rounding order (exact-recheck path).
__device__ __forceinline__ float pd_np(float qx, float qy, float qz, float xxn,
                                       float cx, float cy, float cz, float xm) {
  float p0 = qx * cx;
  float p1 = qy * cy;
  float p2 = qz * cz;
  float dot = (p0 + p1) + p2;
  float t = __builtin_fmaf(dot, 2.0f, -xxn);
  return t - xm;
}

__device__ __forceinline__ void insert20(float (&arr)[K_NN], float v) {
  float c = v;
#pragma unroll
  for (int u = K_NN - 1; u >= 0; --u) {
    float hi = fmaxf(arr[u], c);
    c = fminf(arr[u], c);
    arr[u] = hi;
  }
}

// key = (sortable_pd << 13) | (8191 - j); u64 desc == (pd desc, j asc).
__device__ __forceinline__ void insK(u64k (&a)[K_NN], u64k k) {
  u64k c = k;
#pragma unroll
  for (int u = K_NN - 1; u >= 0; --u) {
    bool g = a[u] > c;
    u64k hi = g ? a[u] : c;
    u64k lo = g ? c : a[u];
    a[u] = hi;
    c = lo;
  }
}

__device__ __forceinline__ unsigned sortable32(float v) {
  unsigned s = __float_as_uint(v);
  return s ^ ((unsigned)((int)s >> 31) | 0x80000000u);
}
__device__ __forceinline__ u64k packKey(float pd, int j) {
  return ((u64k)sortable32(pd) << 13) | (unsigned)(8191 - j);
}
__device__ __forceinline__ float keyPd(u64k k) {
  unsigned sp = (unsigned)(k >> 13);
  unsigned s = (sp & 0x80000000u) ? (sp & 0x7FFFFFFFu) : ~sp;
  return __uint_as_float(s);
}

// Prep: P = {x,y,z,xx} fp32; Bp = 8 bf16 per point {ch0..2, cl0..2, -xxh, -xxl}.
__global__ __launch_bounds__(256, 2)
void prep_kernel(const float* __restrict__ x, float4* __restrict__ P,
                 u16* __restrict__ Bp) {
  int idx = blockIdx.x * 256 + threadIdx.x;
  if (idx >= B_SZ * N_PTS) return;
  int b = idx >> 13, n = idx & (N_PTS - 1);
  const float* xb = x + (size_t)b * 3 * N_PTS;
  float c0 = xb[n], c1 = xb[n + N_PTS], c2 = xb[n + 2 * N_PTS];
  float xx = (c0 * c0 + c1 * c1) + c2 * c2;       // numpy order
  P[idx] = make_float4(c0, c1, c2, xx);
  union { u16 r[8]; uint4 v; } u;
  float cc[3] = {c0, c1, c2};
#pragma unroll
  for (int k = 0; k < 3; ++k) {
    u16 hb = bf16_rn(cc[k]);
    u.r[k] = hb;
    u.r[3 + k] = bf16_rn(cc[k] - bf16_tof(hb));   // low split
  }
  u16 mh = bf16_rn(-xx);
  u.r[6] = mh;
  u.r[7] = bf16_rn(-xx - bf16_tof(mh));
  ((uint4*)Bp)[idx] = u.v;
}

__global__ __launch_bounds__(512, 4)
void knn_edgeconv_kernel(const float4* __restrict__ P,
                         const u16* __restrict__ Bp,
                         const float* __restrict__ W,
                         const float* __restrict__ bias,
                         float* __restrict__ out) {
  __shared__ __align__(16) char raw[49152];
  int*  stk  = (int*)raw;                   // [64][CAPQ] = 30720 B
  u16*  Blds = (u16*)(raw + 30720);         // [512][16]  = 16384 B
  u16*  Alds = (u16*)(raw + 47104);         // [64][16]   = 2048 B
  float* WV  = (float*)raw;                 // warm alias [512*21] = 43008 B
  __shared__ float tau_l[QW];
  __shared__ float xq_l[QW];
  __shared__ int   cnt_l[QW];
  __shared__ int   list_l[QW][21];

  const int t  = threadIdx.x;
  const int ql = t & 63;
  const int s  = t >> 6;
  const int wb = blockIdx.x;                // 0..511
  const int b  = wb >> 7;
  const int n0 = (wb & 127) << 6;
  const int q  = n0 + ql;

  const float4* __restrict__ Pb  = P + (size_t)b * N_PTS;
  const u16*    __restrict__ Bpb = Bp + (size_t)b * N_PTS * 8;

  const float4 qc = Pb[q];
  const float qx = qc.x, qy = qc.y, qz = qc.z, xxn = qc.w;
  const int sw = __builtin_amdgcn_readfirstlane(s);

  // ---- Warm: wave w scans cands [w*64,(w+1)*64) fp32 -> values top-20 ----
  float arrv[K_NN];
#pragma unroll
  for (int i = 0; i < K_NN; ++i) arrv[i] = -__builtin_inff();
  {
    const int jb = sw * WARM;
    for (int jj = 0; jj < WARM; ++jj) {
      float4 cd = Pb[jb + jj];
      float pdv = pd_np(qx, qy, qz, xxn, cd.x, cd.y, cd.z, cd.w);
      if (pdv > arrv[0]) insert20(arrv, pdv);
    }
#pragma unroll
    for (int i = 0; i < K_NN; ++i) WV[t * 21 + i] = arrv[i];
  }
  __syncthreads();

  // ---- Merge -> tau0 (exact 20th of 512-sample); build A rows; init ----
  if (t < QW) {
    float m[K_NN];
#pragma unroll
    for (int i = 0; i < K_NN; ++i) m[i] = -__builtin_inff();
    for (int p = 0; p < NWAVE; ++p) {
      const float* pv = WV + ((p << 6) + t) * 21;
      for (int i = 0; i < K_NN; ++i) {
        float v = pv[i];
        if (v > m[0]) insert20(m, v);
      }
    }
    tau_l[t] = m[0];
    float4 pc = Pb[n0 + t];
    xq_l[t] = pc.w;
    cnt_l[t] = 0;
    // A row t: [2qh(3), 2ql(3), 2qh(3), 1, 1, 0...]
    union { u16 r[16]; uint4 v[2]; } ua;
    float cc[3] = {pc.x, pc.y, pc.z};
#pragma unroll
    for (int k = 0; k < 3; ++k) {
      u16 hb = bf16_rn(cc[k]);
      float hf = bf16_tof(hb);
      u16 lb = bf16_rn(cc[k] - hf);
      u16 h2 = bf16_rn(2.0f * hf);                 // exact (exp+1)
      u16 l2 = bf16_rn(2.0f * bf16_tof(lb));
      ua.r[k] = h2; ua.r[3 + k] = l2; ua.r[6 + k] = h2;
    }
    ua.r[9] = 0x3F80; ua.r[10] = 0x3F80;           // 1.0, 1.0
    ua.r[11] = 0; ua.r[12] = 0; ua.r[13] = 0; ua.r[14] = 0; ua.r[15] = 0;
    ((uint4*)(Alds + t * 16))[0] = ua.v[0];
    ((uint4*)(Alds + t * 16))[1] = ua.v[1];
  }
  __syncthreads();

  // ---- A fragment (fixed per wave): row = rt*16 + (ql&15), k = (ql>>4)*8 ----
  const int rt   = s & 3;                   // row-tile of this wave
  const int kg   = ql >> 4;                 // k-group 0..3
  const int col  = ql & 15;
  bf16x8 afrag;
  if (kg < 2) {
    u16x8 av = *(const u16x8*)(Alds + (rt * 16 + col) * 16 + kg * 8);
    afrag = __builtin_bit_cast(bf16x8, av);
  } else {
    u16x8 z = {0, 0, 0, 0, 0, 0, 0, 0};
    afrag = __builtin_bit_cast(bf16x8, z);
  }

  u64k karr[K_NN];
#pragma unroll
  for (int i = 0; i < K_NN; ++i) karr[i] = 0ULL;

  // ---- Two filter passes: [0,2048) with tau0, [2048,8192) with tau1 ----
  for (int ps = 0; ps < 2; ++ps) {
    const int lo = ps ? P1END : 0;
    const int hi = ps ? N_PTS : P1END;
    float tpe[4];                            // tau' - EPS per my 4 output rows
#pragma unroll
    for (int i = 0; i < 4; ++i) {
      int qr = rt * 16 + ((ql >> 4) << 2) + i;     // C/D row (m89-verified)
      tpe[i] = tau_l[qr] + xq_l[qr] - EPS;
    }
    for (int cb = lo; cb < hi; cb += CHUNK) {
      {       // stage 512 cands: expand 8 -> 16 slots [ch,ch,cl,mh,ml,0..]
        uint4 sv = ((const uint4*)(Bpb + (size_t)(cb + t) * 8))[0];
        unsigned u0 = sv.x, u1 = sv.y, u2 = sv.z, u3 = sv.w;
        uint4 d0, d1;
        d0.x = u0;                                   // c0,c1
        d0.y = (u1 & 0xFFFFu) | (u0 << 16);          // c2,c0
        d0.z = (u0 >> 16) | (u1 << 16);              // c1,c2
        d0.w = (u1 >> 16) | (u2 << 16);              // l0,l1
        d1.x = (u2 >> 16) | (u3 << 16);              // l2,mh
        d1.y = (u3 >> 16);                           // ml,0
        d1.z = 0; d1.w = 0;
        ((uint4*)(Blds + t * 16))[0] = d0;
        ((uint4*)(Blds + t * 16))[1] = d1;
      }
      __syncthreads();
      const int tbase = (s >> 2) * 16;               // waves 0-3 / 4-7 split
#pragma unroll 4
      for (int tt = 0; tt < 16; ++tt) {
        const int tile = tbase + tt;
        bf16x8 bfrag;
        if (kg < 2) {
          u16x8 bv = *(const u16x8*)(Blds + (tile * 16 + col) * 16 + kg * 8);
          bfrag = __builtin_bit_cast(bf16x8, bv);
        } else {
          u16x8 z = {0, 0, 0, 0, 0, 0, 0, 0};
          bfrag = __builtin_bit_cast(bf16x8, z);
        }
        f32x4 acc = {0.0f, 0.0f, 0.0f, 0.0f};
        acc = __builtin_amdgcn_mfma_f32_16x16x32_bf16(afrag, bfrag, acc, 0, 0, 0);
        bool f0 = acc[0] >= tpe[0], f1 = acc[1] >= tpe[1];
        bool f2 = acc[2] >= tpe[2], f3 = acc[3] >= tpe[3];
        if (__ballot(f0 | f1 | f2 | f3)) {
          const int candj = cb + tile * 16 + col;
#pragma unroll
          for (int i = 0; i < 4; ++i) {
            bool fi = (i == 0) ? f0 : (i == 1) ? f1 : (i == 2) ? f2 : f3;
            if (fi) {
              int qr = rt * 16 + ((ql >> 4) << 2) + i;
              int slot = atomicAdd(&cnt_l[qr], 1);
              if (slot < CAPQ) stk[qr * CAPQ + slot] = candj;
            }
          }
        }
      }
      __syncthreads();
    }
    // ---- Drain (exact fp32 recheck): wave sw lanes 0..7 own queries sw*8+ql ----
    if (ql < 8) {
      const int myq = sw * 8 + ql;
      const float tauc = tau_l[myq];
      const int pc = cnt_l[myq];
      float4 mq = Pb[n0 + myq];
      if (pc <= CAPQ) {
        for (int i = 0; i < pc; ++i) {
          int j = stk[myq * CAPQ + i];
          float4 cd = Pb[j];
          float pdv = pd_np(mq.x, mq.y, mq.z, mq.w, cd.x, cd.y, cd.z, cd.w);
          if (pdv >= tauc) {
            u64k k = packKey(pdv, j);
            if (k > karr[0]) insK(karr, k);
          }
        }
      } else {                               // rare: exact whole-range rescan
        for (int j = lo; j < hi; ++j) {
          float4 cd = Pb[j];
          float pdv = pd_np(mq.x, mq.y, mq.z, mq.w, cd.x, cd.y, cd.z, cd.w);
          if (pdv >= tauc) {
            u64k k = packKey(pdv, j);
            if (k > karr[0]) insK(karr, k);
          }
        }
      }
      cnt_l[myq] = 0;
      float t20 = keyPd(karr[0]);            // NaN while not full -> keep old
      tau_l[myq] = fmaxf(tauc, t20);
    }
    __syncthreads();
  }

  // ---- Publish final neighbor indices ----
  if (ql < 8) {
    const int myq = sw * 8 + ql;
#pragma unroll
    for (int i = 0; i < K_NN; ++i)
      list_l[myq][i] = 8191 - (int)(karr[i] & 8191ULL);
  }
  __syncthreads();

  // ---- EdgeConv: max_j( W[:,0:3]·(x_m - x_n) ) + center term, leaky relu ----
  float acc[8];
#pragma unroll
  for (int oi = 0; oi < 8; ++oi) acc[oi] = -__builtin_inff();
  const int o0 = s * 8;
  const float* __restrict__ Wp = W + o0 * 6;

  for (int nb = 0; nb < K_NN; ++nb) {
    int m = list_l[ql][nb] & (N_PTS - 1);    // mask: memory-safety belt
    float4 cm = Pb[m];
    float dx = cm.x - qx;
    float dy = cm.y - qy;
    float dz = cm.z - qz;
#pragma unroll
    for (int oi = 0; oi < 8; ++oi) {
      float h = __builtin_fmaf(dz, Wp[oi * 6 + 2],
                __builtin_fmaf(dy, Wp[oi * 6 + 1], dx * Wp[oi * 6 + 0]));
      acc[oi] = fmaxf(acc[oi], h);
    }
  }

#pragma unroll
  for (int oi = 0; oi < 8; ++oi) {
    int o = o0 + oi;
    float base = __builtin_fmaf(qz, Wp[oi * 6 + 5],
                 __builtin_fmaf(qy, Wp[oi * 6 + 4], qx * Wp[oi * 6 + 3])) + bias[o];
    float v = acc[oi] + base;
    v = fmaxf(v, 0.2f * v);                  // leaky_relu (monotone, commutes with max)
    out[((size_t)(b * O_CH + o) << 13) + q] = v;
  }
}

extern "C" void kernel_launch(void* const* d_in, const int* in_sizes, int n_in,
                              void* d_out, int out_size, void* d_ws, size_t ws_size,
                              hipStream_t stream) {
  const float* x    = (const float*)d_in[0];
  const float* W    = (const float*)d_in[1];
  const float* bias = (const float*)d_in[2];
  char* ws = (char*)d_ws;
  float4* P = (float4*)ws;                           // 512 KB
  u16*    Bp = (u16*)(ws + 512 * 1024);              // 512 KB
  float* out = (float*)d_out;

  prep_kernel<<<dim3((B_SZ * N_PTS + 255) / 256), dim3(256), 0, stream>>>(x, P, Bp);
  knn_edgeconv_kernel<<<dim3(B_SZ * (N_PTS / QW)), dim3(512), 0, stream>>>(
      P, Bp, W, bias, out);
}

// Round 12
// 1076.134 us; speedup vs baseline: 1.4856x; 1.4856x over previous
//
#include <hip/hip_runtime.h>
#include <cstdint>

#pragma clang fp contract(off)

#define N_PTS 8192
#define B_SZ  4
#define K_NN  20
#define O_CH  64
#define QW    32              // queries per block
#define NSUB  14              // scan subsets: 7 scan waves x 2 half-waves
#define SUBL  585             // subset length (last subset gets 587)
#define WARM  32              // warm candidates per subset (union = 448 sample)
#define CAP   8               // survivor stack capacity per (subset,query) chunk
#define SPAD  9               // stack row stride (u64)
#define NCH   5

typedef unsigned long long u64k;

// pd = -xx_n - (-2*dot) - xx_m with numpy rounding order.
// fma(dot,2,-xxn): 2*dot is exact => identical bits to round(2dot - xxn).
__device__ __forceinline__ float pd_np(float qx, float qy, float qz, float xxn,
                                       float cx, float cy, float cz, float xm) {
  float p0 = qx * cx;
  float p1 = qy * cy;
  float p2 = qz * cz;
  float dot = (p0 + p1) + p2;
  float t = __builtin_fmaf(dot, 2.0f, -xxn);
  return t - xm;
}

// values-only gated branchless sorted insert (ascending; keeps 20 largest)
__device__ __forceinline__ void insert20(float (&arr)[K_NN], float v) {
  float c = v;
#pragma unroll
  for (int u = K_NN - 1; u >= 0; --u) {
    float hi = fmaxf(arr[u], c);
    c = fminf(arr[u], c);
    arr[u] = hi;
  }
}

// packed-key sorted insert: key = (sortable_pd << 13) | (8191 - j)
// u64 descending == (pd desc, j asc) == jax.lax.top_k order (set semantics).
__device__ __forceinline__ void insK(u64k (&a)[K_NN], u64k k) {
  u64k c = k;
#pragma unroll
  for (int u = K_NN - 1; u >= 0; --u) {
    bool g = a[u] > c;
    u64k hi = g ? a[u] : c;
    u64k lo = g ? c : a[u];
    a[u] = hi;
    c = lo;
  }
}

__device__ __forceinline__ unsigned sortable32(float pd) {
  unsigned s = __float_as_uint(pd);
  return s ^ ((unsigned)((int)s >> 31) | 0x80000000u);
}

__device__ __forceinline__ u64k packKey(float pd, int j) {
  return ((u64k)sortable32(pd) << 13) | (unsigned)(8191 - j);
}

__device__ __forceinline__ float keyPd(u64k k) {
  unsigned sp = (unsigned)(k >> 13);
  unsigned s = (sp & 0x80000000u) ? (sp & 0x7FFFFFFFu) : ~sp;
  return __uint_as_float(s);
}

__global__ __launch_bounds__(256, 2)
void pack_kernel(const float* __restrict__ x, float4* __restrict__ P) {
  int idx = blockIdx.x * 256 + threadIdx.x;   // b*N + n
  if (idx >= B_SZ * N_PTS) return;
  int b = idx >> 13;
  int n = idx & (N_PTS - 1);
  const float* xb = x + (size_t)b * 3 * N_PTS;
  float x0 = xb[n];
  float x1 = xb[n + N_PTS];
  float x2 = xb[n + 2 * N_PTS];
  float xxv = (x0 * x0 + x1 * x1) + x2 * x2;  // numpy order, no contraction
  P[idx] = make_float4(x0, x1, x2, xxv);
}

__global__ __launch_bounds__(512, 8)
void knn_edgeconv_kernel(const float4* __restrict__ P,
                         const float* __restrict__ W,
                         const float* __restrict__ bias,
                         float* __restrict__ out) {
  // Manual LDS layout, 36864 B total (4 blocks/CU):
  //   stk  [0, 32256)      u64[448][9]   survivor stacks
  //   cnt  [32256, 34048)  int[448]      low16 = cnt, high16 = ofj+1
  //   list [34048, 36736)  int[32][21]   final indices (publish phase only)
  //   tau  [36736, 36864)  float[32]
  //   warm alias [0, 35840) = float[448][20] (dead before cnt/list written)
  __shared__ __align__(16) char raw[36864];
  u64k*  stk    = (u64k*)raw;
  int*   cnt_l  = (int*)(raw + 32256);
  int*   list_l = (int*)(raw + 34048);      // [32][21]
  float* tau_l  = (float*)(raw + 36736);
  float* warmv  = (float*)raw;              // [448][20]

  const int t  = threadIdx.x;
  const int ql = t & 63;
  const int s  = t >> 6;              // wave id: 0 = drain, 1..7 = scan
  const int qi = ql & 31;             // my query within block
  const int hf = ql >> 5;             // half-wave 0/1
  const int wb = blockIdx.x;          // 0..1023
  const int b  = wb >> 8;
  const int n0 = (wb & 255) << 5;
  const int q  = n0 + qi;

  const float4* __restrict__ Pb = P + (size_t)b * N_PTS;

  const float4 qc = Pb[q];
  const float qx = qc.x, qy = qc.y, qz = qc.z, xxn = qc.w;

  const int sw    = __builtin_amdgcn_readfirstlane(s);
  const int sid   = (sw - 1) * 2 + hf;          // subset id 0..13 (scan waves)
  const int j0    = sid * SUBL;
  const int LEN   = (sid == NSUB - 1) ? (N_PTS - (NSUB - 1) * SUBL) : SUBL; // 587 last
  const int row   = sid * QW + qi;              // stack row 0..447
  const int CB[NCH + 1] = {0, 32, 96, 224, 480, SUBL};

  // ---- Warm-up (scan waves): values-only top-20 of first WARM own candidates ----
  float arrv[K_NN];
#pragma unroll
  for (int i = 0; i < K_NN; ++i) arrv[i] = -__builtin_inff();
  if (s >= 1) {
#pragma unroll 4
    for (int jj = 0; jj < WARM; ++jj) {
      float4 cd = Pb[j0 + jj];
      float pdv = pd_np(qx, qy, qz, xxn, cd.x, cd.y, cd.z, cd.w);
      if (pdv > arrv[0]) insert20(arrv, pdv);
    }
#pragma unroll
    for (int i = 0; i < K_NN; ++i) warmv[row * K_NN + i] = arrv[i];
  }
  __syncthreads();

  // ---- Drain wave lanes <32: merge 14 warm lists -> tau0 (exact 20th of 448) ----
  u64k karr[K_NN];
#pragma unroll
  for (int i = 0; i < K_NN; ++i) karr[i] = 0ULL;
  if (s == 0 && ql < QW) {
    float m[K_NN];
#pragma unroll
    for (int i = 0; i < K_NN; ++i) m[i] = -__builtin_inff();
    for (int p = 0; p < NSUB; ++p) {
      const float* pv = warmv + (p * QW + ql) * K_NN;
      for (int i = 0; i < K_NN; ++i) {
        float v = pv[i];
        if (v > m[0]) insert20(m, v);
      }
    }
    tau_l[ql] = m[0];
  }
  __syncthreads();                    // warm data dead; stk/cnt live from here

  // ---- Chunked filtered scan (waves 1-7) + barrier-serial drain (wave 0) ----
  for (int c = 0; c < NCH; ++c) {
    if (s >= 1) {
      const float tau = tau_l[qi];
      int cnt = 0, ofj = -1;
      const int jb = j0 + CB[c];
      const int je = j0 + ((c == NCH - 1) ? LEN : CB[c + 1]);
      u64k* my = stk + (size_t)row * SPAD;
#pragma unroll 4
      for (int j = jb; j < je; ++j) {
        float4 cd = Pb[j];
        float pdv = pd_np(qx, qy, qz, xxn, cd.x, cd.y, cd.z, cd.w);
        if (pdv >= tau) {               // >= : keep boundary ties
          if (cnt < CAP) { my[cnt] = packKey(pdv, j); ++cnt; }
          else if (ofj < 0) ofj = j - j0;   // deterministic overflow marker
        }
      }
      cnt_l[row] = cnt | ((ofj + 1) << 16);
    }
    __syncthreads();

    if (s == 0 && ql < QW) {            // drain: lane ql owns query ql
      const float tauc = tau_l[ql];
      for (int p = 0; p < NSUB; ++p) {
        const int pr = p * QW + ql;
        const int v  = cnt_l[pr];
        const int pc = v & 0xFFFF;
        const u64k* ps = stk + (size_t)pr * SPAD;
        for (int i = 0; i < pc; ++i) {
          u64k k = ps[i];
          if (k > karr[0]) insK(karr, k);
        }
      }
      for (int p = 0; p < NSUB; ++p) {  // rare: exact overflow-tail rescan
        const int pr = p * QW + ql;
        const int oj = (cnt_l[pr] >> 16) - 1;
        if (oj >= 0) {
          const int pj0 = p * SUBL;
          const int plen = (p == NSUB - 1) ? (N_PTS - (NSUB - 1) * SUBL) : SUBL;
          const int pje = pj0 + ((c == NCH - 1) ? plen : CB[c + 1]);
          for (int j = pj0 + oj; j < pje; ++j) {
            float4 cd = Pb[j];
            float pdv = pd_np(qx, qy, qz, xxn, cd.x, cd.y, cd.z, cd.w);
            if (pdv >= tauc) {
              u64k k = packKey(pdv, j);
              if (k > karr[0]) insK(karr, k);
            }
          }
        }
      }
      float t20 = keyPd(karr[0]);       // NaN while karr not full -> fmaxf keeps old
      tau_l[ql] = fmaxf(tauc, t20);
    }
    __syncthreads();
  }

  // ---- Publish final neighbor indices ----
  if (s == 0 && ql < QW) {
#pragma unroll
    for (int i = 0; i < K_NN; ++i)
      list_l[ql * 21 + i] = 8191 - (int)(karr[i] & 8191ULL);
  }
  __syncthreads();

  // ---- EdgeConv: max_j( W[:,0:3]·(x_m - x_n) ) + center term, leaky relu ----
  // thread t handles (query t&31, channels (t>>5)*4 .. +3)
  float acc[4];
#pragma unroll
  for (int oi = 0; oi < 4; ++oi) acc[oi] = -__builtin_inff();
  const int o0 = (t >> 5) * 4;
  const float* __restrict__ Wp = W + o0 * 6;

  for (int nb = 0; nb < K_NN; ++nb) {
    int m = list_l[qi * 21 + nb] & (N_PTS - 1);   // mask: memory-safety belt
    float4 cm = Pb[m];
    float dx = cm.x - qx;
    float dy = cm.y - qy;
    float dz = cm.z - qz;
#pragma unroll
    for (int oi = 0; oi < 4; ++oi) {
      float h = __builtin_fmaf(dz, Wp[oi * 6 + 2],
                __builtin_fmaf(dy, Wp[oi * 6 + 1], dx * Wp[oi * 6 + 0]));
      acc[oi] = fmaxf(acc[oi], h);
    }
  }

#pragma unroll
  for (int oi = 0; oi < 4; ++oi) {
    int o = o0 + oi;
    float base = __builtin_fmaf(qz, Wp[oi * 6 + 5],
                 __builtin_fmaf(qy, Wp[oi * 6 + 4], qx * Wp[oi * 6 + 3])) + bias[o];
    float v = acc[oi] + base;
    v = fmaxf(v, 0.2f * v);                 // leaky_relu (monotone, commutes with max)
    out[((size_t)(b * O_CH + o) << 13) + q] = v;
  }
}

extern "C" void kernel_launch(void* const* d_in, const int* in_sizes, int n_in,
                              void* d_out, int out_size, void* d_ws, size_t ws_size,
                              hipStream_t stream) {
  const float* x    = (const float*)d_in[0];
  const float* W    = (const float*)d_in[1];
  const float* bias = (const float*)d_in[2];
  float4* P  = (float4*)d_ws;               // B*N float4 = 512 KB
  float* out = (float*)d_out;

  pack_kernel<<<dim3((B_SZ * N_PTS + 255) / 256), dim3(256), 0, stream>>>(x, P);
  knn_edgeconv_kernel<<<dim3(B_SZ * (N_PTS / QW)), dim3(512), 0, stream>>>(P, W, bias, out);
}